// Round 6
// baseline (703.741 us; speedup 1.0000x reference)
//
#include <hip/hip_runtime.h>

// GCN 2-layer forward for MI355X.
// x[N,128] @ W1 -> aggregate -> +b1 -> relu -> @ W2 -> aggregate -> +b2.
// Aggregation: out[dst] += h[src] * dis[src]*dis[dst]; self-loop (norm=dis^2)
// folded into the output-init kernel. dis = rsqrt(in-degree incl. self-loop).
//
// Defensive posture (unverified on HW so far; rounds 0/2/3/4/5 were infra
// failures, round 1 was the int64-index crash, fixed):
//  - ws_size checked before any launch; insufficient ws -> no launches
//    (harness reports wrong-answer instead of a device fault).
//  - all gathered/scattered indices clamped to [0, N) so a wrong dtype
//    assumption yields a wrong answer + profile, not a wedged container.

#define IN_DIM 128
#define H_DIM 48
#define O_DIM 32

__device__ __forceinline__ int clampi(int v, int hi) {
    return v < 0 ? 0 : (v >= hi ? hi - 1 : v);
}

// ---------------- degree / dis ----------------

__global__ void k_init_deg(float* __restrict__ deg, int n) {
    int i = blockIdx.x * blockDim.x + threadIdx.x;
    if (i < n) deg[i] = 1.0f;  // self-loop contribution
}

__global__ void k_deg_edges(const int* __restrict__ dst, float* __restrict__ deg,
                            int E, int N) {
    int e = blockIdx.x * blockDim.x + threadIdx.x;
    if (e < E) unsafeAtomicAdd(&deg[clampi(dst[e], N)], 1.0f);
}

__global__ void k_rsqrt_inplace(float* __restrict__ d, int n) {
    int i = blockIdx.x * blockDim.x + threadIdx.x;
    if (i < n) d[i] = rsqrtf(d[i]);  // deg >= 1 always (self-loop)
}

// ---------------- GEMM: H[n, NO] = X[n, K] @ W[K, NO] ----------------

template <int K, int NO>
__global__ __launch_bounds__(256) void k_gemm(const float* __restrict__ X,
                                              const float* __restrict__ W,
                                              float* __restrict__ H, int n) {
    constexpr int BM = 32;
    constexpr int JPT = NO / 8;
    __shared__ float xs[BM * (K + 1)];
    __shared__ float ws[K * NO];

    const int t = threadIdx.x;
    const int node0 = blockIdx.x * BM;

    for (int i = t; i < K * NO; i += 256) ws[i] = W[i];
    for (int i = t; i < BM * K; i += 256) {
        int r = i / K, k = i % K;
        int node = node0 + r;
        xs[r * (K + 1) + k] = (node < n) ? X[(long long)node * K + k] : 0.0f;
    }
    __syncthreads();

    const int r = t >> 3;
    const int g = t & 7;
    float acc[JPT];
#pragma unroll
    for (int jj = 0; jj < JPT; jj++) acc[jj] = 0.0f;

    for (int k = 0; k < K; k++) {
        float xv = xs[r * (K + 1) + k];
#pragma unroll
        for (int jj = 0; jj < JPT; jj++) acc[jj] += xv * ws[k * NO + g * JPT + jj];
    }

    int node = node0 + r;
    if (node < n) {
#pragma unroll
        for (int jj = 0; jj < JPT; jj++)
            H[(long long)node * NO + g * JPT + jj] = acc[jj];
    }
}

// ---------------- aggregation ----------------

// out[n*F + j] = h[n*F + j] * dis[n]^2  (+ optional bias): the self-loop edge.
template <int F, bool BIAS>
__global__ void k_selfloop_init(const float* __restrict__ h, const float* __restrict__ dis,
                                const float* __restrict__ bias, float* __restrict__ out,
                                int total) {
    int i = blockIdx.x * blockDim.x + threadIdx.x;
    if (i >= total) return;
    int n = i / F;
    float d = dis[n];
    float v = h[i] * d * d;
    if (BIAS) v += bias[i % F];
    out[i] = v;
}

// one thread per (edge, feature); norm computed inline from dis (L2-resident).
template <int F>
__global__ void k_agg(const int* __restrict__ src, const int* __restrict__ dst,
                      const float* __restrict__ dis, const float* __restrict__ h,
                      float* __restrict__ out, unsigned total, int N) {
    unsigned t = blockIdx.x * blockDim.x + threadIdx.x;
    if (t >= total) return;
    unsigned e = t / F;
    unsigned j = t - e * F;
    int s = clampi(src[e], N);
    int d = clampi(dst[e], N);
    float nrm = dis[s] * dis[d];
    float v = h[(long long)s * F + j] * nrm;
    unsafeAtomicAdd(&out[(long long)d * F + j], v);
}

__global__ void k_bias_relu(float* __restrict__ z, const float* __restrict__ b, int total) {
    int i = blockIdx.x * blockDim.x + threadIdx.x;
    if (i >= total) return;
    z[i] = fmaxf(z[i] + b[i % H_DIM], 0.0f);
}

// ---------------- launch ----------------

static inline unsigned cdiv(unsigned a, unsigned b) { return (a + b - 1) / b; }

extern "C" void kernel_launch(void* const* d_in, const int* in_sizes, int n_in,
                              void* d_out, int out_size, void* d_ws, size_t ws_size,
                              hipStream_t stream) {
    const float* x = (const float*)d_in[0];
    const int* ei = (const int*)d_in[1];   // int32 per harness convention
    const float* W1 = (const float*)d_in[2];
    const float* b1 = (const float*)d_in[3];
    const float* W2 = (const float*)d_in[4];
    const float* b2 = (const float*)d_in[5];
    float* out = (float*)d_out;

    const int N = in_sizes[0] / IN_DIM;      // 100000
    const int E = in_sizes[1] / 2;           // 1600000
    const int* src = ei;
    const int* dst = ei + E;

    // ws carve (all f32)
    auto align_up = [](size_t v) { return (v + 63) & ~(size_t)63; };
    size_t off_dis = 0;
    size_t off_h   = off_dis + align_up((size_t)N);
    size_t off_z   = off_h + align_up((size_t)N * H_DIM);
    size_t need    = (off_z + align_up((size_t)N * H_DIM)) * sizeof(float);
    if (ws_size < need) return;  // diagnostic: wrong-answer, not a device fault

    float* dis = (float*)d_ws + off_dis;   // N
    float* h   = (float*)d_ws + off_h;     // N*48 (h1, reused as h2)
    float* z   = (float*)d_ws + off_z;     // N*48
    float* h2  = h;                        // h1 dead once z built

    const int B = 256;

    // ---- normalization ----
    k_init_deg<<<cdiv(N, B), B, 0, stream>>>(dis, N);
    k_deg_edges<<<cdiv(E, B), B, 0, stream>>>(dst, dis, E, N);
    k_rsqrt_inplace<<<cdiv(N, B), B, 0, stream>>>(dis, N);

    // ---- layer 1 ----
    k_gemm<IN_DIM, H_DIM><<<cdiv(N, 32), B, 0, stream>>>(x, W1, h, N);
    k_selfloop_init<H_DIM, false><<<cdiv(N * H_DIM, B), B, 0, stream>>>(h, dis, b1, z, N * H_DIM);
    {
        unsigned total = (unsigned)E * H_DIM;  // 76.8M
        k_agg<H_DIM><<<cdiv(total, B), B, 0, stream>>>(src, dst, dis, h, z, total, N);
    }
    k_bias_relu<<<cdiv(N * H_DIM, B), B, 0, stream>>>(z, b1, N * H_DIM);

    // ---- layer 2 ----
    k_gemm<H_DIM, O_DIM><<<cdiv(N, 32), B, 0, stream>>>(z, W2, h2, N);
    k_selfloop_init<O_DIM, true><<<cdiv(N * O_DIM, B), B, 0, stream>>>(h2, dis, b2, out, N * O_DIM);
    {
        unsigned total = (unsigned)E * O_DIM;  // 51.2M
        k_agg<O_DIM><<<cdiv(total, B), B, 0, stream>>>(src, dst, dis, h2, out, total, N);
    }
}

// Round 8
// 535.455 us; speedup vs baseline: 1.3143x; 1.3143x over previous
//
#include <hip/hip_runtime.h>

// GCN 2-layer forward for MI355X — round 7/8: CSR pull aggregation.
//
// Round-6 baseline (703.7 us): k_agg<48> = 253 us at 300 G atomics/s,
// WRITE_SIZE == 4B * n_atomics -> device-scope f32 atomics write through the
// fabric one by one; aggregation was atomic-throughput-bound (26% HBM peak).
//
// This round: build CSR by dst per call (histogram -> 2-level scan -> fill),
// then pull-aggregate: one wave per dst node, lanes = features, per-edge
// coalesced gather of h[src], single accumulator register, no atomics on the
// feature data. Self-loop + bias + relu folded into the pull epilogue.
// Fallback: if ws_size can't fit the CSR (+53 MB total), run the proven
// round-6 push path (ws_size is call-invariant -> capture-safe branching).

#define IN_DIM 128
#define H_DIM 48
#define O_DIM 32

__device__ __forceinline__ int clampi(int v, int hi) {
    return v < 0 ? 0 : (v >= hi ? hi - 1 : v);
}

// ======================= CSR build =======================

__global__ void k_zero_i32(int* __restrict__ p, int n) {
    int i = blockIdx.x * blockDim.x + threadIdx.x;
    if (i < n) p[i] = 0;
}

__global__ void k_count(const int* __restrict__ dst, int* __restrict__ cnt,
                        int E, int N) {
    int e = blockIdx.x * blockDim.x + threadIdx.x;
    if (e < E) atomicAdd(&cnt[clampi(dst[e], N)], 1);
}

// block-level exclusive scan of cnt -> rp (local), block totals -> bsum
__global__ __launch_bounds__(1024) void k_scan1(const int* __restrict__ cnt,
                                                int* __restrict__ rp,
                                                int* __restrict__ bsum, int n) {
    __shared__ int sh[1024];
    const int tid = threadIdx.x;
    const int i = blockIdx.x * 1024 + tid;
    int v = (i < n) ? cnt[i] : 0;
    sh[tid] = v;
    __syncthreads();
    for (int off = 1; off < 1024; off <<= 1) {
        int t = (tid >= off) ? sh[tid - off] : 0;
        __syncthreads();
        sh[tid] += t;
        __syncthreads();
    }
    if (i < n) rp[i] = sh[tid] - v;  // exclusive
    if (tid == 1023) bsum[blockIdx.x] = sh[1023];
}

// single-block exclusive scan of the <=128 block totals (in place)
__global__ __launch_bounds__(128) void k_scan2(int* __restrict__ bsum, int nb) {
    __shared__ int sh[128];
    const int tid = threadIdx.x;
    int v = (tid < nb) ? bsum[tid] : 0;
    sh[tid] = v;
    __syncthreads();
    for (int off = 1; off < 128; off <<= 1) {
        int t = (tid >= off) ? sh[tid - off] : 0;
        __syncthreads();
        sh[tid] += t;
        __syncthreads();
    }
    if (tid < nb) bsum[tid] = sh[tid] - v;  // exclusive
}

// rp += block offset; cursor = rp; dis = rsqrt(1 + cnt); rp[n] = E
__global__ void k_scan3(int* __restrict__ rp, const int* __restrict__ bsum,
                        int* __restrict__ cur, const int* __restrict__ cnt,
                        float* __restrict__ dis, int n, int E) {
    int i = blockIdx.x * blockDim.x + threadIdx.x;
    if (i < n) {
        int r = rp[i] + bsum[i >> 10];
        rp[i] = r;
        cur[i] = r;
        dis[i] = rsqrtf(1.0f + (float)cnt[i]);
    }
    if (i == 0) rp[n] = E;
}

// scatter edges into dst-sorted order; payload = {src, dis[src]}
__global__ void k_fill(const int* __restrict__ src, const int* __restrict__ dst,
                       const float* __restrict__ dis, int* __restrict__ cur,
                       int2* __restrict__ srt, int E, int N) {
    int e = blockIdx.x * blockDim.x + threadIdx.x;
    if (e >= E) return;
    int s = clampi(src[e], N);
    int d = clampi(dst[e], N);
    int p = atomicAdd(&cur[d], 1);
    srt[p] = make_int2(s, __float_as_int(dis[s]));
}

// ======================= GEMM =======================

template <int K, int NO>
__global__ __launch_bounds__(256) void k_gemm(const float* __restrict__ X,
                                              const float* __restrict__ W,
                                              float* __restrict__ H, int n) {
    constexpr int BM = 32;
    constexpr int JPT = NO / 8;
    __shared__ float xs[BM * (K + 1)];
    __shared__ float ws[K * NO];

    const int t = threadIdx.x;
    const int node0 = blockIdx.x * BM;

    for (int i = t; i < K * NO; i += 256) ws[i] = W[i];
    for (int i = t; i < BM * K; i += 256) {
        int r = i / K, k = i % K;
        int node = node0 + r;
        xs[r * (K + 1) + k] = (node < n) ? X[(long long)node * K + k] : 0.0f;
    }
    __syncthreads();

    const int r = t >> 3;
    const int g = t & 7;
    float acc[JPT];
#pragma unroll
    for (int jj = 0; jj < JPT; jj++) acc[jj] = 0.0f;

    for (int k = 0; k < K; k++) {
        float xv = xs[r * (K + 1) + k];
#pragma unroll
        for (int jj = 0; jj < JPT; jj++) acc[jj] += xv * ws[k * NO + g * JPT + jj];
    }

    int node = node0 + r;
    if (node < n) {
#pragma unroll
        for (int jj = 0; jj < JPT; jj++)
            H[(long long)node * NO + g * JPT + jj] = acc[jj];
    }
}

// ======================= pull aggregation =======================
// One wave per dst node. F=48: lanes 0..47 = features, 1 edge/iter (2x unroll).
// F=32: lane = half*32 + feature, 2 edges/iter, shfl_xor(32) reduce at end.
// Epilogue: + self-loop (h[d]*dis^2) + bias (+relu for layer 1).

template <int F, bool RELU>
__global__ __launch_bounds__(256) void k_pull(const int2* __restrict__ srt,
                                              const int* __restrict__ rp,
                                              const float* __restrict__ dis,
                                              const float* __restrict__ hbuf,
                                              const float* __restrict__ bias,
                                              float* __restrict__ out, int N) {
    const int w = blockIdx.x * 4 + (threadIdx.x >> 6);
    if (w >= N) return;
    const int lane = threadIdx.x & 63;
    const int beg = rp[w];
    const int end = rp[w + 1];
    const float disd = dis[w];
    float acc = 0.0f;

    if (F == 48) {
        const int j = lane;
        if (j < F) {
            int e = beg;
            for (; e + 1 < end; e += 2) {
                int2 p0 = srt[e];
                int2 p1 = srt[e + 1];
                float v0 = hbuf[(size_t)p0.x * F + j];
                float v1 = hbuf[(size_t)p1.x * F + j];
                acc = fmaf(v0, __int_as_float(p0.y) * disd, acc);
                acc = fmaf(v1, __int_as_float(p1.y) * disd, acc);
            }
            if (e < end) {
                int2 p = srt[e];
                acc = fmaf(hbuf[(size_t)p.x * F + j], __int_as_float(p.y) * disd, acc);
            }
            float val = acc + hbuf[(size_t)w * F + j] * disd * disd + bias[j];
            if (RELU) val = fmaxf(val, 0.0f);
            out[(size_t)w * F + j] = val;
        }
    } else {  // F == 32
        const int j = lane & 31;
        const int half = lane >> 5;
        for (int e = beg + half; e < end; e += 2) {
            int2 p = srt[e];
            acc = fmaf(hbuf[(size_t)p.x * F + j], __int_as_float(p.y) * disd, acc);
        }
        acc += __shfl_xor(acc, 32);
        if (lane < 32) {
            float val = acc + hbuf[(size_t)w * F + j] * disd * disd + bias[j];
            if (RELU) val = fmaxf(val, 0.0f);
            out[(size_t)w * F + j] = val;
        }
    }
}

// ======================= fallback push path (round-6, proven) =======================

__global__ void k_init_deg(float* __restrict__ deg, int n) {
    int i = blockIdx.x * blockDim.x + threadIdx.x;
    if (i < n) deg[i] = 1.0f;
}

__global__ void k_deg_edges(const int* __restrict__ dst, float* __restrict__ deg,
                            int E, int N) {
    int e = blockIdx.x * blockDim.x + threadIdx.x;
    if (e < E) unsafeAtomicAdd(&deg[clampi(dst[e], N)], 1.0f);
}

__global__ void k_rsqrt_inplace(float* __restrict__ d, int n) {
    int i = blockIdx.x * blockDim.x + threadIdx.x;
    if (i < n) d[i] = rsqrtf(d[i]);
}

template <int F, bool BIAS>
__global__ void k_selfloop_init(const float* __restrict__ h, const float* __restrict__ dis,
                                const float* __restrict__ bias, float* __restrict__ out,
                                int total) {
    int i = blockIdx.x * blockDim.x + threadIdx.x;
    if (i >= total) return;
    int n = i / F;
    float d = dis[n];
    float v = h[i] * d * d;
    if (BIAS) v += bias[i % F];
    out[i] = v;
}

template <int F>
__global__ void k_agg(const int* __restrict__ src, const int* __restrict__ dst,
                      const float* __restrict__ dis, const float* __restrict__ h,
                      float* __restrict__ out, unsigned total, int N) {
    unsigned t = blockIdx.x * blockDim.x + threadIdx.x;
    if (t >= total) return;
    unsigned e = t / F;
    unsigned j = t - e * F;
    int s = clampi(src[e], N);
    int d = clampi(dst[e], N);
    float v = h[(long long)s * F + j] * (dis[s] * dis[d]);
    unsafeAtomicAdd(&out[(long long)d * F + j], v);
}

__global__ void k_bias_relu(float* __restrict__ z, const float* __restrict__ b, int total) {
    int i = blockIdx.x * blockDim.x + threadIdx.x;
    if (i >= total) return;
    z[i] = fmaxf(z[i] + b[i % H_DIM], 0.0f);
}

// ======================= launch =======================

static inline unsigned cdiv(unsigned a, unsigned b) { return (a + b - 1) / b; }

extern "C" void kernel_launch(void* const* d_in, const int* in_sizes, int n_in,
                              void* d_out, int out_size, void* d_ws, size_t ws_size,
                              hipStream_t stream) {
    const float* x = (const float*)d_in[0];
    const int* ei = (const int*)d_in[1];   // int32 (verified round 6)
    const float* W1 = (const float*)d_in[2];
    const float* b1 = (const float*)d_in[3];
    const float* W2 = (const float*)d_in[4];
    const float* b2 = (const float*)d_in[5];
    float* out = (float*)d_out;

    const int N = in_sizes[0] / IN_DIM;      // 100000
    const int E = in_sizes[1] / 2;           // 1600000
    const int* src = ei;
    const int* dst = ei + E;
    const int NB = (int)cdiv(N, 1024);       // scan blocks (98)

    const int B = 256;
    char* base = (char*)d_ws;

    // ---- pull-path carve ----
    size_t off = 0;
    auto carve = [&](size_t bytes) { size_t o = off; off = (off + bytes + 255) & ~(size_t)255; return o; };
    size_t o_dis  = carve((size_t)N * 4);
    size_t o_cnt  = carve((size_t)N * 4);
    size_t o_rp   = carve(((size_t)N + 1) * 4);
    size_t o_cur  = carve((size_t)N * 4);
    size_t o_bsum = carve(256 * 4);
    size_t o_srt  = carve((size_t)E * 8);
    size_t o_h    = carve((size_t)N * H_DIM * 4);
    size_t o_z    = carve((size_t)N * H_DIM * 4);
    size_t need_pull = off;

    if (ws_size >= need_pull && NB <= 128) {
        float* dis = (float*)(base + o_dis);
        int*   cnt = (int*)(base + o_cnt);
        int*   rp  = (int*)(base + o_rp);
        int*   cur = (int*)(base + o_cur);
        int*   bsm = (int*)(base + o_bsum);
        int2*  srt = (int2*)(base + o_srt);
        float* h   = (float*)(base + o_h);
        float* z   = (float*)(base + o_z);
        float* h2  = h;  // h1 dead once z built; layer-2 gemm output reuses it

        // CSR build
        k_zero_i32<<<cdiv(N, B), B, 0, stream>>>(cnt, N);
        k_count<<<cdiv(E, B), B, 0, stream>>>(dst, cnt, E, N);
        k_scan1<<<NB, 1024, 0, stream>>>(cnt, rp, bsm, N);
        k_scan2<<<1, 128, 0, stream>>>(bsm, NB);
        k_scan3<<<cdiv(N, B), B, 0, stream>>>(rp, bsm, cur, cnt, dis, N, E);
        k_fill<<<cdiv(E, B), B, 0, stream>>>(src, dst, dis, cur, srt, E, N);

        // layer 1
        k_gemm<IN_DIM, H_DIM><<<cdiv(N, 32), B, 0, stream>>>(x, W1, h, N);
        k_pull<H_DIM, true><<<cdiv(N, 4), B, 0, stream>>>(srt, rp, dis, h, b1, z, N);

        // layer 2
        k_gemm<H_DIM, O_DIM><<<cdiv(N, 32), B, 0, stream>>>(z, W2, h2, N);
        k_pull<O_DIM, false><<<cdiv(N, 4), B, 0, stream>>>(srt, rp, dis, h2, b2, out, N);
        return;
    }

    // ---- fallback: proven round-6 push path ----
    auto align_up = [](size_t v) { return (v + 63) & ~(size_t)63; };
    size_t f_dis = 0;
    size_t f_h   = f_dis + align_up((size_t)N);
    size_t f_z   = f_h + align_up((size_t)N * H_DIM);
    size_t need_push = (f_z + align_up((size_t)N * H_DIM)) * sizeof(float);
    if (ws_size < need_push) return;

    float* dis = (float*)d_ws + f_dis;
    float* h   = (float*)d_ws + f_h;
    float* z   = (float*)d_ws + f_z;
    float* h2  = h;

    k_init_deg<<<cdiv(N, B), B, 0, stream>>>(dis, N);
    k_deg_edges<<<cdiv(E, B), B, 0, stream>>>(dst, dis, E, N);
    k_rsqrt_inplace<<<cdiv(N, B), B, 0, stream>>>(dis, N);

    k_gemm<IN_DIM, H_DIM><<<cdiv(N, 32), B, 0, stream>>>(x, W1, h, N);
    k_selfloop_init<H_DIM, false><<<cdiv(N * H_DIM, B), B, 0, stream>>>(h, dis, b1, z, N * H_DIM);
    k_agg<H_DIM><<<cdiv((unsigned)E * H_DIM, B), B, 0, stream>>>(src, dst, dis, h, z, (unsigned)E * H_DIM, N);
    k_bias_relu<<<cdiv(N * H_DIM, B), B, 0, stream>>>(z, b1, N * H_DIM);

    k_gemm<H_DIM, O_DIM><<<cdiv(N, 32), B, 0, stream>>>(z, W2, h2, N);
    k_selfloop_init<O_DIM, true><<<cdiv(N * O_DIM, B), B, 0, stream>>>(h2, dis, b2, out, N * O_DIM);
    k_agg<O_DIM><<<cdiv((unsigned)E * O_DIM, B), B, 0, stream>>>(src, dst, dis, h2, out, (unsigned)E * O_DIM, N);
}